// Round 2
// baseline (388.781 us; speedup 1.0000x reference)
//
#include <hip/hip_runtime.h>
#include <hip/hip_bf16.h>
#include <stdint.h>

#define N_TOK 32768
#define D_IN  1024
#define U_OUT 1024

typedef __attribute__((ext_vector_type(4))) int int32x4;

__device__ __forceinline__ void async_copy16(const void* g, void* l) {
  __builtin_amdgcn_global_load_lds(
      (const __attribute__((address_space(1))) void*)g,
      (__attribute__((address_space(3))) void*)l,
      16, 0, 0);
}

// ---------------------------------------------------------------------------
// Kernel 1: per-row sign quantization (int8 ±1) + beta = mean(|x|) per row.
// One 64-lane wave per row; 4 waves (4 rows) per 256-thread block.
// Lane owns 16 consecutive floats -> one 16B i8 store.
// ---------------------------------------------------------------------------
__global__ __launch_bounds__(256) void quant_kernel(
    const float* __restrict__ x,
    char* __restrict__ xq,            // i8 {+1,-1} [N_TOK][D_IN]
    float* __restrict__ beta) {
  const int wave = threadIdx.x >> 6;
  const int lane = threadIdx.x & 63;
  const int row  = blockIdx.x * 4 + wave;

  const float4* p = (const float4*)(x + (size_t)row * D_IN);
  alignas(16) char sb[16];
  float asum = 0.f;
  #pragma unroll
  for (int j = 0; j < 4; ++j) {
    const float4 v = p[lane * 4 + j];
    asum += fabsf(v.x) + fabsf(v.y) + fabsf(v.z) + fabsf(v.w);
    sb[j * 4 + 0] = (v.x >= 0.f) ? 1 : -1;
    sb[j * 4 + 1] = (v.y >= 0.f) ? 1 : -1;
    sb[j * 4 + 2] = (v.z >= 0.f) ? 1 : -1;
    sb[j * 4 + 3] = (v.w >= 0.f) ? 1 : -1;
  }
  *(int32x4*)(xq + (size_t)row * D_IN + lane * 16) = *(const int32x4*)sb;

  #pragma unroll
  for (int off = 32; off > 0; off >>= 1)
    asum += __shfl_down(asum, off, 64);
  if (lane == 0) beta[row] = asum * (1.0f / (float)D_IN);
}

// ---------------------------------------------------------------------------
// Kernel 2: W[d,u] = sum_e a_e[u]*sign(k_e[d,u]); per-column i8 quantization.
// q[u] = max_d |W[d,u]| / 127;  wt_i8[u][d] = rint(W[d,u]/q[u])  (transposed:
// GEMM B-operand contiguous in K=d). 16 blocks, each owns 64 u-columns.
// Thread (ul=tid&63, dg=tid>>6) covers d in [dg*256, dg*256+256).
// Pass 1 finds the max, pass 2 (L2-hot re-read, 12 MB total) quantizes.
// ---------------------------------------------------------------------------
__global__ __launch_bounds__(256) void wt_kernel(
    const float* __restrict__ k0, const float* __restrict__ k1,
    const float* __restrict__ k2,
    const float* __restrict__ a0, const float* __restrict__ a1,
    const float* __restrict__ a2,
    char* __restrict__ wt,            // i8 [U_OUT][D_IN]
    float* __restrict__ q) {          // f32 [U_OUT]
  const int tid = threadIdx.x;
  const int ul  = tid & 63;
  const int dg  = tid >> 6;
  const int u   = blockIdx.x * 64 + ul;
  const float av0 = a0[u], av1 = a1[u], av2 = a2[u];

  // pass 1: column max
  float mx = 0.f;
  for (int j = 0; j < 256; ++j) {
    const size_t idx = (size_t)(dg * 256 + j) * U_OUT + u;
    const float w = (k0[idx] >= 0.f ? av0 : -av0)
                  + (k1[idx] >= 0.f ? av1 : -av1)
                  + (k2[idx] >= 0.f ? av2 : -av2);
    mx = fmaxf(mx, fabsf(w));
  }
  __shared__ float smax[4][64];
  smax[dg][ul] = mx;
  __syncthreads();
  const float m4 = fmaxf(fmaxf(smax[0][ul], smax[1][ul]),
                         fmaxf(smax[2][ul], smax[3][ul]));
  const float qv  = fmaxf(m4, 1e-20f) * (1.0f / 127.0f);
  const float inv = 127.0f / fmaxf(m4, 1e-20f);
  if (dg == 0) q[u] = qv;

  // pass 2: quantize + store 16B chunks (contiguous 256B per thread)
  for (int c = 0; c < 16; ++c) {
    alignas(16) char buf[16];
    #pragma unroll
    for (int j = 0; j < 16; ++j) {
      const size_t idx = (size_t)(dg * 256 + c * 16 + j) * U_OUT + u;
      const float w = (k0[idx] >= 0.f ? av0 : -av0)
                    + (k1[idx] >= 0.f ? av1 : -av1)
                    + (k2[idx] >= 0.f ? av2 : -av2);
      int v = (int)rintf(w * inv);
      v = v > 127 ? 127 : (v < -127 ? -127 : v);
      buf[j] = (char)v;
    }
    *(int32x4*)(wt + (size_t)u * D_IN + dg * 256 + c * 16) =
        *(const int32x4*)buf;
  }
}

// ---------------------------------------------------------------------------
// Kernel 3: C[n,u] = beta[n]*q[u] * (Xq[n,:] . Wt[u,:])  -- i8 MFMA GEMM.
// A = Xq [M,K] i8; Bt = Wt [N,K] i8. 128x128 tile, BK=64 (64B rows), 4 waves
// in 2x2, each wave 4x4 mfma_i32_16x16x64_i8 (exact i32 accumulation).
// XCD swizzle: xcd = bid&7 gets a contiguous band of 32 m-tiles, with the 8
// n-tiles innermost -> the 8 blocks sharing an A-tile are temporally adjacent
// on the SAME XCD's L2 (per-XCD L2s are not cross-coherent/shared).
// ---------------------------------------------------------------------------
#define BM 128
#define BN 128
#define BK 64

__global__ __launch_bounds__(256, 2) void gemm_kernel(
    const char* __restrict__ A,       // [M,K] i8
    const char* __restrict__ Bt,      // [N,K] i8
    const float* __restrict__ beta,
    const float* __restrict__ q,
    float* __restrict__ C) {
  const int K = D_IN, N = U_OUT;
  __shared__ char As[BM * BK];        // 8 KB, lane-ordered (global_load_lds)
  __shared__ char Bs[BN * BK];        // 8 KB

  const int bid = blockIdx.x;
  const int xcd = bid & 7;            // dispatch round-robins XCDs by bid
  const int g   = bid >> 3;           // 0..255 = per-XCD sequence
  const int mt  = xcd * 32 + (g >> 3);
  const int nt  = g & 7;
  const int m0  = mt * BM;
  const int n0  = nt * BN;

  const int tid  = threadIdx.x;
  const int wave = tid >> 6;
  const int lane = tid & 63;
  const int wr   = wave >> 1;
  const int wc   = wave & 1;
  const int lrow = lane & 15;
  const int quad = lane >> 4;

  int32x4 acc[4][4] = {};

  for (int kk = 0; kk < K; kk += BK) {
    // stage A/B tiles: 512 x 16B segments each, 2 per thread
    #pragma unroll
    for (int half = 0; half < 2; half++) {
      const int s   = tid + half * 256;   // 0..511
      const int row = s >> 2;             // 0..127
      const int c   = (s & 3) * 16;       // bytes within 64B row
      async_copy16(A  + (size_t)(m0 + row) * K + kk + c, As + (size_t)s * 16);
      async_copy16(Bt + (size_t)(n0 + row) * K + kk + c, Bs + (size_t)s * 16);
    }
    __syncthreads();

    int32x4 af[4], bf[4];
    #pragma unroll
    for (int i = 0; i < 4; i++) {
      af[i] = *(const int32x4*)(As + (wr * 64 + i * 16 + lrow) * BK + quad * 16);
      bf[i] = *(const int32x4*)(Bs + (wc * 64 + i * 16 + lrow) * BK + quad * 16);
    }
    #pragma unroll
    for (int mi = 0; mi < 4; mi++)
      #pragma unroll
      for (int ni = 0; ni < 4; ni++)
        acc[mi][ni] = __builtin_amdgcn_mfma_i32_16x16x64_i8(
            af[mi], bf[ni], acc[mi][ni], 0, 0, 0);
    __syncthreads();
  }

  // epilogue: C/D layout col=lane&15, row=quad*4+reg (dtype-independent)
  #pragma unroll
  for (int mi = 0; mi < 4; mi++) {
    #pragma unroll
    for (int r = 0; r < 4; r++) {
      const int row = m0 + wr * 64 + mi * 16 + quad * 4 + r;
      const float b = beta[row];
      #pragma unroll
      for (int ni = 0; ni < 4; ni++) {
        const int col = n0 + wc * 64 + ni * 16 + lrow;
        C[(size_t)row * N + col] = (float)acc[mi][ni][r] * b * q[col];
      }
    }
  }
}

// ---------------------------------------------------------------------------
extern "C" void kernel_launch(void* const* d_in, const int* in_sizes, int n_in,
                              void* d_out, int out_size, void* d_ws, size_t ws_size,
                              hipStream_t stream) {
  const float* x  = (const float*)d_in[0];
  const float* k0 = (const float*)d_in[1];
  const float* k1 = (const float*)d_in[2];
  const float* k2 = (const float*)d_in[3];
  const float* a0 = (const float*)d_in[4];
  const float* a1 = (const float*)d_in[5];
  const float* a2 = (const float*)d_in[6];
  float* out = (float*)d_out;

  char* ws = (char*)d_ws;
  char*  xq   = ws;                                          // 32 MiB
  char*  wt   = ws + (size_t)N_TOK * D_IN;                   // 1 MiB
  float* q    = (float*)(wt + (size_t)U_OUT * D_IN);         // 4 KiB
  float* beta = q + U_OUT;                                   // 128 KiB

  quant_kernel<<<N_TOK / 4, 256, 0, stream>>>(x, xq, beta);
  wt_kernel<<<U_OUT / 64, 256, 0, stream>>>(k0, k1, k2, a0, a1, a2, wt, q);
  gemm_kernel<<<(N_TOK / BM) * (U_OUT / BN), 256, 0, stream>>>(xq, wt, beta, q, out);
}

// Round 3
// 289.055 us; speedup vs baseline: 1.3450x; 1.3450x over previous
//
#include <hip/hip_runtime.h>
#include <hip/hip_bf16.h>
#include <stdint.h>

#define N_TOK 32768
#define D_IN  1024
#define U_OUT 1024

typedef __attribute__((ext_vector_type(4))) int int32x4;

__device__ __forceinline__ void async_copy16(const void* g, void* l) {
  __builtin_amdgcn_global_load_lds(
      (const __attribute__((address_space(1))) void*)g,
      (__attribute__((address_space(3))) void*)l,
      16, 0, 0);
}

// ---------------------------------------------------------------------------
// Kernel 1: per-row sign quantization (int8 ±1) + beta = mean(|x|) per row.
// One 64-lane wave per row; 4 waves (4 rows) per 256-thread block.
// ---------------------------------------------------------------------------
__global__ __launch_bounds__(256) void quant_kernel(
    const float* __restrict__ x,
    char* __restrict__ xq,            // i8 {+1,-1} [N_TOK][D_IN]
    float* __restrict__ beta) {
  const int wave = threadIdx.x >> 6;
  const int lane = threadIdx.x & 63;
  const int row  = blockIdx.x * 4 + wave;

  const float4* p = (const float4*)(x + (size_t)row * D_IN);
  alignas(16) char sb[16];
  float asum = 0.f;
  #pragma unroll
  for (int j = 0; j < 4; ++j) {
    const float4 v = p[lane * 4 + j];
    asum += fabsf(v.x) + fabsf(v.y) + fabsf(v.z) + fabsf(v.w);
    sb[j * 4 + 0] = (v.x >= 0.f) ? 1 : -1;
    sb[j * 4 + 1] = (v.y >= 0.f) ? 1 : -1;
    sb[j * 4 + 2] = (v.z >= 0.f) ? 1 : -1;
    sb[j * 4 + 3] = (v.w >= 0.f) ? 1 : -1;
  }
  *(int32x4*)(xq + (size_t)row * D_IN + lane * 16) = *(const int32x4*)sb;

  #pragma unroll
  for (int off = 32; off > 0; off >>= 1)
    asum += __shfl_down(asum, off, 64);
  if (lane == 0) beta[row] = asum * (1.0f / (float)D_IN);
}

// ---------------------------------------------------------------------------
// Kernel 2 (rewritten): W[d,u] = sum_e a_e[u]*sign(k_e[d,u]).
// Since W[d,u] = +-a0 +-a1 +-a2, |W[:,u]| <= a0[u]+a1[u]+a2[u] EXACTLY, so
// q[u] = (a0+a1+a2)/127 needs no scan over d. Single pass:
//   64 blocks; block b owns d-rows [16b,16b+16); thread owns 4 u-columns.
//   Per-d reads are full coalesced 4KB rows; transposed 16B-row writes are
//   assembled in registers (no LDS).
// ---------------------------------------------------------------------------
__global__ __launch_bounds__(256) void wt_kernel(
    const float* __restrict__ k0, const float* __restrict__ k1,
    const float* __restrict__ k2,
    const float* __restrict__ a0, const float* __restrict__ a1,
    const float* __restrict__ a2,
    char* __restrict__ wt,            // i8 [U_OUT][D_IN]
    float* __restrict__ q) {          // f32 [U_OUT]
  const int tid = threadIdx.x;
  const int d0  = blockIdx.x * 16;
  const int u0  = tid * 4;

  const float4 av0 = *(const float4*)(a0 + u0);
  const float4 av1 = *(const float4*)(a1 + u0);
  const float4 av2 = *(const float4*)(a2 + u0);
  float4 s;
  s.x = fmaxf(av0.x + av1.x + av2.x, 1e-20f);
  s.y = fmaxf(av0.y + av1.y + av2.y, 1e-20f);
  s.z = fmaxf(av0.z + av1.z + av2.z, 1e-20f);
  s.w = fmaxf(av0.w + av1.w + av2.w, 1e-20f);
  if (blockIdx.x == 0) {
    float4 qv;
    qv.x = s.x * (1.0f / 127.0f); qv.y = s.y * (1.0f / 127.0f);
    qv.z = s.z * (1.0f / 127.0f); qv.w = s.w * (1.0f / 127.0f);
    *(float4*)(q + u0) = qv;
  }
  const float4 inv = {127.0f / s.x, 127.0f / s.y, 127.0f / s.z, 127.0f / s.w};

  alignas(16) char buf[4][16];      // [u_local][d_local] output rows
  #pragma unroll
  for (int d = 0; d < 16; ++d) {
    const size_t off = (size_t)(d0 + d) * U_OUT + u0;
    const float4 v0 = *(const float4*)(k0 + off);
    const float4 v1 = *(const float4*)(k1 + off);
    const float4 v2 = *(const float4*)(k2 + off);
    float4 w;
    w.x = (v0.x >= 0.f ? av0.x : -av0.x) + (v1.x >= 0.f ? av1.x : -av1.x)
        + (v2.x >= 0.f ? av2.x : -av2.x);
    w.y = (v0.y >= 0.f ? av0.y : -av0.y) + (v1.y >= 0.f ? av1.y : -av1.y)
        + (v2.y >= 0.f ? av2.y : -av2.y);
    w.z = (v0.z >= 0.f ? av0.z : -av0.z) + (v1.z >= 0.f ? av1.z : -av1.z)
        + (v2.z >= 0.f ? av2.z : -av2.z);
    w.w = (v0.w >= 0.f ? av0.w : -av0.w) + (v1.w >= 0.f ? av1.w : -av1.w)
        + (v2.w >= 0.f ? av2.w : -av2.w);
    buf[0][d] = (char)(int)rintf(w.x * inv.x);
    buf[1][d] = (char)(int)rintf(w.y * inv.y);
    buf[2][d] = (char)(int)rintf(w.z * inv.z);
    buf[3][d] = (char)(int)rintf(w.w * inv.w);
  }
  #pragma unroll
  for (int j = 0; j < 4; ++j)
    *(int32x4*)(wt + (size_t)(u0 + j) * D_IN + d0) = *(const int32x4*)buf[j];
}

// ---------------------------------------------------------------------------
// Kernel 3: C[n,u] = beta[n]*q[u] * (Xq[n,:] . Wt[u,:])  -- i8 MFMA GEMM.
// 128x128 tile, BK=64, 4 waves 2x2, mfma_i32_16x16x64_i8 (exact i32 acc).
// XCD swizzle: xcd = bid&7 owns a contiguous band of 32 m-tiles, 8 n-tiles
// innermost -> A-tile re-reads hit the same XCD's L2.
// ---------------------------------------------------------------------------
#define BM 128
#define BN 128
#define BK 64

__global__ __launch_bounds__(256, 2) void gemm_kernel(
    const char* __restrict__ A,       // [M,K] i8
    const char* __restrict__ Bt,      // [N,K] i8
    const float* __restrict__ beta,
    const float* __restrict__ q,
    float* __restrict__ C) {
  const int K = D_IN, N = U_OUT;
  __shared__ char As[BM * BK];
  __shared__ char Bs[BN * BK];

  const int bid = blockIdx.x;
  const int xcd = bid & 7;
  const int g   = bid >> 3;
  const int mt  = xcd * 32 + (g >> 3);
  const int nt  = g & 7;
  const int m0  = mt * BM;
  const int n0  = nt * BN;

  const int tid  = threadIdx.x;
  const int wave = tid >> 6;
  const int lane = tid & 63;
  const int wr   = wave >> 1;
  const int wc   = wave & 1;
  const int lrow = lane & 15;
  const int quad = lane >> 4;

  int32x4 acc[4][4] = {};

  for (int kk = 0; kk < K; kk += BK) {
    #pragma unroll
    for (int half = 0; half < 2; half++) {
      const int s   = tid + half * 256;   // 0..511
      const int row = s >> 2;             // 0..127
      const int c   = (s & 3) * 16;       // bytes within 64B row
      async_copy16(A  + (size_t)(m0 + row) * K + kk + c, As + (size_t)s * 16);
      async_copy16(Bt + (size_t)(n0 + row) * K + kk + c, Bs + (size_t)s * 16);
    }
    __syncthreads();

    int32x4 af[4], bf[4];
    #pragma unroll
    for (int i = 0; i < 4; i++) {
      af[i] = *(const int32x4*)(As + (wr * 64 + i * 16 + lrow) * BK + quad * 16);
      bf[i] = *(const int32x4*)(Bs + (wc * 64 + i * 16 + lrow) * BK + quad * 16);
    }
    #pragma unroll
    for (int mi = 0; mi < 4; mi++)
      #pragma unroll
      for (int ni = 0; ni < 4; ni++)
        acc[mi][ni] = __builtin_amdgcn_mfma_i32_16x16x64_i8(
            af[mi], bf[ni], acc[mi][ni], 0, 0, 0);
    __syncthreads();
  }

  // epilogue: C/D layout col=lane&15, row=quad*4+reg (dtype-independent)
  #pragma unroll
  for (int mi = 0; mi < 4; mi++) {
    #pragma unroll
    for (int r = 0; r < 4; r++) {
      const int row = m0 + wr * 64 + mi * 16 + quad * 4 + r;
      const float b = beta[row];
      #pragma unroll
      for (int ni = 0; ni < 4; ni++) {
        const int col = n0 + wc * 64 + ni * 16 + lrow;
        C[(size_t)row * N + col] = (float)acc[mi][ni][r] * b * q[col];
      }
    }
  }
}

// ---------------------------------------------------------------------------
extern "C" void kernel_launch(void* const* d_in, const int* in_sizes, int n_in,
                              void* d_out, int out_size, void* d_ws, size_t ws_size,
                              hipStream_t stream) {
  const float* x  = (const float*)d_in[0];
  const float* k0 = (const float*)d_in[1];
  const float* k1 = (const float*)d_in[2];
  const float* k2 = (const float*)d_in[3];
  const float* a0 = (const float*)d_in[4];
  const float* a1 = (const float*)d_in[5];
  const float* a2 = (const float*)d_in[6];
  float* out = (float*)d_out;

  char* ws = (char*)d_ws;
  char*  xq   = ws;                                          // 32 MiB
  char*  wt   = ws + (size_t)N_TOK * D_IN;                   // 1 MiB
  float* q    = (float*)(wt + (size_t)U_OUT * D_IN);         // 4 KiB
  float* beta = q + U_OUT;                                   // 128 KiB

  quant_kernel<<<N_TOK / 4, 256, 0, stream>>>(x, xq, beta);
  wt_kernel<<<64, 256, 0, stream>>>(k0, k1, k2, a0, a1, a2, wt, q);
  gemm_kernel<<<(N_TOK / BM) * (U_OUT / BN), 256, 0, stream>>>(xq, wt, beta, q, out);
}